// Round 5
// baseline (256.820 us; speedup 1.0000x reference)
//
#include <hip/hip_runtime.h>

#define NN 50000
#define EE 400000
#define CIN 16
#define COUT 32
#define NTILES (EE / 32)

typedef float f32x4  __attribute__((ext_vector_type(4)));
typedef float f32x16 __attribute__((ext_vector_type(16)));
typedef short short8 __attribute__((ext_vector_type(8)));

// ================= Path A layout (needs ~55 MB ws) =================
#define A_DEG    0                         // int degi[NN]
#define A_NCUR   200000                    // int node_cur[NN]
#define A_HIST   400000                    // int hist[64]
#define A_CUR    400256                    // int cursors[64]
#define A_SUM    400512                    // float gsum[32]
#define A_SUMSQ  400640                    // float gsumsq[32]
#define A_ZERO   400768
#define A_NOFF   400768                    // int node_off[NN+1]
#define A_SORT   (A_NOFF + 200064)         // int sorted[EE]
#define A_BYD    (A_SORT + 1600000)        // int by_dst[EE]
#define A_MSG    (A_BYD + 1600000)         // float msgs[EE*COUT]
#define A_NEED   ((size_t)A_MSG + (size_t)EE * COUT * 4)

// ================= Path B layout (R4 fallback, ~8.2 MB) =================
#define B_AGG   0
#define B_DEG   (NN*COUT*4)
#define B_HIST  (B_DEG + NN*4)
#define B_CUR   (B_HIST + 256)
#define B_SUM   (B_CUR + 256)
#define B_SUMSQ (B_SUM + 128)
#define B_ZERO  (B_SUMSQ + 128)
#define B_OFFS  B_ZERO
#define B_SORT  (B_OFFS + 512)

__device__ __forceinline__ void cell_of(float a0, float a1, float a2,
                                        int& l0, int& l1, int& l2,
                                        float& f0, float& f1, float& f2) {
  float v0 = a0 * 4.0f, v1 = a1 * 4.0f, v2 = a2 * 4.0f;
  l0 = min(max((int)v0, 0), 3);
  l1 = min(max((int)v1, 0), 3);
  l2 = min(max((int)v2, 0), 3);
  f0 = v0 - (float)l0; f1 = v1 - (float)l1; f2 = v2 - (float)l2;
}

// ---------- shared: per-cell histogram + in-degree ----------
__global__ void k_hist(const float* __restrict__ attr, const int* __restrict__ edst,
                       int* __restrict__ hist, int* __restrict__ degi) {
  __shared__ int lh[64];
  if (threadIdx.x < 64) lh[threadIdx.x] = 0;
  __syncthreads();
  for (int e = blockIdx.x * blockDim.x + threadIdx.x; e < EE; e += gridDim.x * blockDim.x) {
    int l0, l1, l2; float f0, f1, f2;
    cell_of(attr[e*3], attr[e*3+1], attr[e*3+2], l0, l1, l2, f0, f1, f2);
    atomicAdd(&lh[l0 | (l1 << 2) | (l2 << 4)], 1);
    atomicAdd(&degi[edst[e]], 1);
  }
  __syncthreads();
  if (threadIdx.x < 64 && lh[threadIdx.x]) atomicAdd(&hist[threadIdx.x], lh[threadIdx.x]);
}

// ---------- Path A: 50k prefix scan of degi -> node_off ----------
__global__ __launch_bounds__(1024) void k_scan(const int* __restrict__ degi,
                                               int* __restrict__ node_off) {
  __shared__ int part[1024];
  int t = threadIdx.x;
  const int CH = 49;  // 1024*49 >= 50000
  int b = t * CH, e = min(b + CH, NN);
  int s = 0;
  for (int i = b; i < e; ++i) s += degi[i];
  part[t] = s;
  __syncthreads();
  for (int d = 1; d < 1024; d <<= 1) {
    int v = (t >= d) ? part[t - d] : 0;
    __syncthreads();
    part[t] += v;
    __syncthreads();
  }
  int run = part[t] - s;  // exclusive base for this chunk
  for (int i = b; i < e; ++i) { node_off[i] = run; run += degi[i]; }
  if (t == 1023) node_off[NN] = part[1023];
}

// ---------- Path A: scatter into cell buckets + dst-CSR fill ----------
__global__ void k_scatterA(const float* __restrict__ attr, const int* __restrict__ edst,
                           const int* __restrict__ hist, int* __restrict__ cursors,
                           int* __restrict__ node_cur, const int* __restrict__ node_off,
                           int* __restrict__ sorted, int* __restrict__ by_dst) {
  __shared__ int lcnt[64], lbase[64], lcur[64], coff[64];
  int tid = threadIdx.x;
  if (tid < 64) { lcnt[tid] = 0; lcur[tid] = 0; }
  if (tid == 0) { int r = 0; for (int c = 0; c < 64; ++c) { coff[c] = r; r += hist[c]; } }
  __syncthreads();
  int per = (EE + gridDim.x - 1) / gridDim.x;
  int b0 = blockIdx.x * per;
  int b1 = min(b0 + per, EE);
  for (int e = b0 + tid; e < b1; e += blockDim.x) {
    int l0, l1, l2; float f0, f1, f2;
    cell_of(attr[e*3], attr[e*3+1], attr[e*3+2], l0, l1, l2, f0, f1, f2);
    atomicAdd(&lcnt[l0 | (l1 << 2) | (l2 << 4)], 1);
  }
  __syncthreads();
  if (tid < 64 && lcnt[tid]) lbase[tid] = coff[tid] + atomicAdd(&cursors[tid], lcnt[tid]);
  __syncthreads();
  for (int e = b0 + tid; e < b1; e += blockDim.x) {
    int l0, l1, l2; float f0, f1, f2;
    cell_of(attr[e*3], attr[e*3+1], attr[e*3+2], l0, l1, l2, f0, f1, f2);
    int c = l0 | (l1 << 2) | (l2 << 4);
    int q = lbase[c] + atomicAdd(&lcur[c], 1);
    sorted[q] = e;
    int d = edst[e];
    int pos = node_off[d] + atomicAdd(&node_cur[d], 1);
    by_dst[pos] = q;
  }
}

// ---------- Path A: MFMA edge kernel, plain stores, NO atomics ----------
// Operand-swapped: A = weight frag (lane&31 = output row), B = edge frag
// (lane&31 = edge slot). D[o][edge]: lane holds 16 outputs of ITS OWN edge
// (dst lane-local, no shfl), stored as 4x dwordx4 to msgs[q][.].
__global__ __launch_bounds__(256) void k_edge_mfma_st(
    const float* __restrict__ x, const int* __restrict__ esrc,
    const float* __restrict__ attr, const float* __restrict__ weight,
    const int* __restrict__ sorted, float* __restrict__ msgs) {
  int gwave = (int)((blockIdx.x * blockDim.x + threadIdx.x) >> 6);
  if (gwave >= NTILES) return;
  int lane = threadIdx.x & 63;
  int col = lane & 31;
  int half = lane >> 5;

  int p = gwave * 32 + col;
  int e = sorted[p];
  float a0 = attr[e*3+0], a1 = attr[e*3+1], a2 = attr[e*3+2];
  int src = esrc[e];

  float v0 = a0 * 4.0f, v1 = a1 * 4.0f, v2 = a2 * 4.0f;
  int l0 = min(max((int)v0, 0), 3);
  int l1 = min(max((int)v1, 0), 3);
  int l2 = min(max((int)v2, 0), 3);
  float f0 = v0 - (float)l0, f1 = v1 - (float)l1, f2 = v2 - (float)l2;
  int mycell = l0 | (l1 << 2) | (l2 << 4);

  const float* xp = x + src * CIN + half * 8;
  float xs[8];
  {
    f32x4 xa = *(const f32x4*)xp;
    f32x4 xb = *(const f32x4*)(xp + 4);
#pragma unroll
    for (int j = 0; j < 4; ++j) { xs[j] = xa[j]; xs[j + 4] = xb[j]; }
  }

  int c_first = __builtin_amdgcn_readfirstlane(mycell);
  int c_last  = __builtin_amdgcn_readfirstlane(__shfl(mycell, 31, 64));
  int npass = (c_first == c_last) ? 1 : 2;

  f32x16 acc;
#pragma unroll
  for (int r = 0; r < 16; ++r) acc[r] = 0.0f;

  float g0 = 1.0f - f0, g1 = 1.0f - f1, g2 = 1.0f - f2;

  for (int pass = 0; pass < npass; ++pass) {
    int cell = pass ? c_last : c_first;
    int c0 = cell & 3, c1 = (cell >> 2) & 3, c2 = cell >> 4;
    bool act = (mycell == cell);
#pragma unroll
    for (int cb = 0; cb < 8; ++cb) {
      float w = ((cb & 1) ? f0 : g0) * (((cb >> 1) & 1) ? f1 : g1) * (((cb >> 2) & 1) ? f2 : g2);
      w = act ? w : 0.0f;
      short8 ev;  // edge operand (w * xs) bf16
#pragma unroll
      for (int j = 0; j < 8; ++j)
        ev[j] = __builtin_bit_cast(short, (__bf16)(w * xs[j]));
      int wi = (c0 + (cb & 1)) + 5 * (c1 + ((cb >> 1) & 1)) + 25 * (c2 + (cb >> 2));
      const float* wp = weight + wi * (CIN * COUT) + (half * 8) * COUT + col;
      short8 wv;  // weight operand W[k][o], o = lane&31
#pragma unroll
      for (int j = 0; j < 8; ++j)
        wv[j] = __builtin_bit_cast(short, (__bf16)wp[j * COUT]);
      // swapped: weights as A, edges as B -> D[o][edge]
      acc = __builtin_amdgcn_mfma_f32_32x32x16_bf16(wv, ev, acc, 0, 0, 0);
    }
  }

  // D layout: col(lane&31)=edge, row r -> o=(r&3)+8*(r>>2)+4*half
  float* mp = msgs + (size_t)p * COUT + 4 * half;
#pragma unroll
  for (int g = 0; g < 4; ++g) {
    f32x4 v;
    v[0] = acc[4*g + 0]; v[1] = acc[4*g + 1]; v[2] = acc[4*g + 2]; v[3] = acc[4*g + 3];
    *(f32x4*)(mp + 8 * g) = v;
  }
}

// ---------- Path A: CSR gather + root + ELU + BN stats ----------
__global__ __launch_bounds__(256) void k_nodeA(
    const float* __restrict__ x, const float* __restrict__ msgs,
    const int* __restrict__ by_dst, const int* __restrict__ node_off,
    const float* __restrict__ root, const float* __restrict__ bias,
    float* __restrict__ hout, float* __restrict__ gsum, float* __restrict__ gsumsq) {
  int tid = threadIdx.x;
  int o = tid & 31;
  int nl = tid >> 5;
  int n = blockIdx.x * 8 + nl;
  float s1 = 0.0f, s2 = 0.0f;
  if (n < NN) {
    int k0 = node_off[n], k1 = node_off[n + 1];
    float s = 0.0f;
    for (int k = k0; k < k1; ++k) {
      int q = by_dst[k];
      s += msgs[(size_t)q * COUT + o];
    }
    float a = s / fmaxf((float)(k1 - k0), 1.0f);
    const float* xp = x + n * CIN;
    float r = 0.0f;
#pragma unroll
    for (int i = 0; i < CIN; ++i) r = fmaf(xp[i], root[i * COUT + o], r);
    float hv = a + r + bias[o];
    hv = hv > 0.0f ? hv : expm1f(hv);
    hout[n * COUT + o] = hv;
    s1 = hv; s2 = hv * hv;
  }
  s1 += __shfl_xor(s1, 32);
  s2 += __shfl_xor(s2, 32);
  __shared__ float sred[2][4][32];
  int w = tid >> 6;
  if ((tid & 63) < 32) { sred[0][w][o] = s1; sred[1][w][o] = s2; }
  __syncthreads();
  if (tid < 32) {
    float t1 = 0.0f, t2 = 0.0f;
#pragma unroll
    for (int w2 = 0; w2 < 4; ++w2) { t1 += sred[0][w2][o]; t2 += sred[1][w2][o]; }
    atomicAdd(&gsum[o], t1);
    atomicAdd(&gsumsq[o], t2);
  }
}

// ---------- shared: finalize BatchNorm in-place ----------
__global__ void k_bn(float* __restrict__ out, const float* __restrict__ gsum,
                     const float* __restrict__ gsumsq, const float* __restrict__ gamma,
                     const float* __restrict__ beta) {
  int idx = blockIdx.x * blockDim.x + threadIdx.x;
  if (idx >= NN * COUT) return;
  int o = idx & 31;
  float m = gsum[o] * (1.0f / NN);
  float var = gsumsq[o] * (1.0f / NN) - m * m;
  float inv = rsqrtf(var + 1e-5f);
  out[idx] = (out[idx] - m) * inv * gamma[o] + beta[o];
}

// ================= Path B (R4 fallback, atomics) =================
__global__ void k_prefixB(const int* __restrict__ hist, int* __restrict__ offsets) {
  if (threadIdx.x == 0) {
    int r = 0;
    for (int c = 0; c < 64; ++c) { offsets[c] = r; r += hist[c]; }
    offsets[64] = r;
  }
}

__global__ void k_scatterB(const float* __restrict__ attr, const int* __restrict__ offsets,
                           int* __restrict__ cursors, int* __restrict__ sorted) {
  __shared__ int lcnt[64], lbase[64], lcur[64];
  int tid = threadIdx.x;
  if (tid < 64) { lcnt[tid] = 0; lcur[tid] = 0; }
  __syncthreads();
  int per = (EE + gridDim.x - 1) / gridDim.x;
  int b0 = blockIdx.x * per;
  int b1 = min(b0 + per, EE);
  for (int e = b0 + tid; e < b1; e += blockDim.x) {
    int l0, l1, l2; float f0, f1, f2;
    cell_of(attr[e*3], attr[e*3+1], attr[e*3+2], l0, l1, l2, f0, f1, f2);
    atomicAdd(&lcnt[l0 | (l1 << 2) | (l2 << 4)], 1);
  }
  __syncthreads();
  if (tid < 64 && lcnt[tid]) lbase[tid] = offsets[tid] + atomicAdd(&cursors[tid], lcnt[tid]);
  __syncthreads();
  for (int e = b0 + tid; e < b1; e += blockDim.x) {
    int l0, l1, l2; float f0, f1, f2;
    cell_of(attr[e*3], attr[e*3+1], attr[e*3+2], l0, l1, l2, f0, f1, f2);
    int c = l0 | (l1 << 2) | (l2 << 4);
    int p = atomicAdd(&lcur[c], 1);
    sorted[lbase[c] + p] = e;
  }
}

__global__ __launch_bounds__(256) void k_edge_atomic(
    const float* __restrict__ x, const int* __restrict__ esrc, const int* __restrict__ edst,
    const float* __restrict__ attr, const float* __restrict__ weight,
    const int* __restrict__ sorted, float* __restrict__ agg) {
  int gwave = (int)((blockIdx.x * blockDim.x + threadIdx.x) >> 6);
  if (gwave >= NTILES) return;
  int lane = threadIdx.x & 63;
  int col = lane & 31;
  int half = lane >> 5;

  int p = gwave * 32 + col;
  int e = sorted[p];
  float a0 = attr[e*3+0], a1 = attr[e*3+1], a2 = attr[e*3+2];
  int src = esrc[e];
  int dst = edst[e];

  float v0 = a0 * 4.0f, v1 = a1 * 4.0f, v2 = a2 * 4.0f;
  int l0 = min(max((int)v0, 0), 3);
  int l1 = min(max((int)v1, 0), 3);
  int l2 = min(max((int)v2, 0), 3);
  float f0 = v0 - (float)l0, f1 = v1 - (float)l1, f2 = v2 - (float)l2;
  int mycell = l0 | (l1 << 2) | (l2 << 4);

  const float* xp = x + src * CIN + half * 8;
  float xs[8];
  {
    f32x4 xa = *(const f32x4*)xp;
    f32x4 xb = *(const f32x4*)(xp + 4);
#pragma unroll
    for (int j = 0; j < 4; ++j) { xs[j] = xa[j]; xs[j + 4] = xb[j]; }
  }

  int c_first = __builtin_amdgcn_readfirstlane(mycell);
  int c_last  = __builtin_amdgcn_readfirstlane(__shfl(mycell, 31, 64));
  int npass = (c_first == c_last) ? 1 : 2;

  f32x16 acc;
#pragma unroll
  for (int r = 0; r < 16; ++r) acc[r] = 0.0f;

  float g0 = 1.0f - f0, g1 = 1.0f - f1, g2 = 1.0f - f2;

  for (int pass = 0; pass < npass; ++pass) {
    int cell = pass ? c_last : c_first;
    int c0 = cell & 3, c1 = (cell >> 2) & 3, c2 = cell >> 4;
    bool act = (mycell == cell);
#pragma unroll
    for (int cb = 0; cb < 8; ++cb) {
      float w = ((cb & 1) ? f0 : g0) * (((cb >> 1) & 1) ? f1 : g1) * (((cb >> 2) & 1) ? f2 : g2);
      w = act ? w : 0.0f;
      short8 av;
#pragma unroll
      for (int j = 0; j < 8; ++j)
        av[j] = __builtin_bit_cast(short, (__bf16)(w * xs[j]));
      int wi = (c0 + (cb & 1)) + 5 * (c1 + ((cb >> 1) & 1)) + 25 * (c2 + (cb >> 2));
      const float* wp = weight + wi * (CIN * COUT) + (half * 8) * COUT + col;
      short8 bv;
#pragma unroll
      for (int j = 0; j < 8; ++j)
        bv[j] = __builtin_bit_cast(short, (__bf16)wp[j * COUT]);
      acc = __builtin_amdgcn_mfma_f32_32x32x16_bf16(av, bv, acc, 0, 0, 0);
    }
  }

#pragma unroll
  for (int r = 0; r < 16; ++r) {
    int orow = (r & 3) + 8 * (r >> 2) + 4 * half;
    int d = __shfl(dst, orow, 64);
    atomicAdd(&agg[d * COUT + col], acc[r]);
  }
}

__global__ __launch_bounds__(1024) void k_nodeB(
    const float* __restrict__ x, const float* __restrict__ agg, const int* __restrict__ degi,
    const float* __restrict__ root, const float* __restrict__ bias,
    float* __restrict__ hout, float* __restrict__ gsum, float* __restrict__ gsumsq) {
  __shared__ float sred[2][16][32];
  int tid = threadIdx.x;
  int o = tid & 31;
  int nl = tid >> 5;
  int n = blockIdx.x * 32 + nl;
  float s1 = 0.0f, s2 = 0.0f;
  if (n < NN) {
    float a = agg[n * COUT + o] / fmaxf((float)degi[n], 1.0f);
    const float* xp = x + n * CIN;
    float r = 0.0f;
#pragma unroll
    for (int i = 0; i < CIN; ++i) r = fmaf(xp[i], root[i * COUT + o], r);
    float hv = a + r + bias[o];
    hv = hv > 0.0f ? hv : expm1f(hv);
    hout[n * COUT + o] = hv;
    s1 = hv; s2 = hv * hv;
  }
  s1 += __shfl_xor(s1, 32);
  s2 += __shfl_xor(s2, 32);
  int w = tid >> 6;
  if ((tid & 63) < 32) { sred[0][w][o] = s1; sred[1][w][o] = s2; }
  __syncthreads();
  if (tid < 32) {
    float t1 = 0.0f, t2 = 0.0f;
#pragma unroll
    for (int w2 = 0; w2 < 16; ++w2) { t1 += sred[0][w2][o]; t2 += sred[1][w2][o]; }
    atomicAdd(&gsum[o], t1);
    atomicAdd(&gsumsq[o], t2);
  }
}

extern "C" void kernel_launch(void* const* d_in, const int* in_sizes, int n_in,
                              void* d_out, int out_size, void* d_ws, size_t ws_size,
                              hipStream_t stream) {
  const float* x      = (const float*)d_in[0];
  const int*   ei     = (const int*)d_in[1];
  const float* attr   = (const float*)d_in[2];
  const float* weight = (const float*)d_in[3];
  const float* root   = (const float*)d_in[4];
  const float* bias   = (const float*)d_in[5];
  const float* gamma  = (const float*)d_in[6];
  const float* beta   = (const float*)d_in[7];
  float* out = (float*)d_out;
  char* ws = (char*)d_ws;
  const int* esrc = ei;
  const int* edst = ei + EE;

  if (ws_size >= A_NEED) {
    // -------- Path A: store + CSR gather (no float atomics) --------
    int*   degi    = (int*)(ws + A_DEG);
    int*   ncur    = (int*)(ws + A_NCUR);
    int*   hist    = (int*)(ws + A_HIST);
    int*   cursors = (int*)(ws + A_CUR);
    float* gsum    = (float*)(ws + A_SUM);
    float* gsumsq  = (float*)(ws + A_SUMSQ);
    int*   noff    = (int*)(ws + A_NOFF);
    int*   sorted  = (int*)(ws + A_SORT);
    int*   by_dst  = (int*)(ws + A_BYD);
    float* msgs    = (float*)(ws + A_MSG);

    hipMemsetAsync(ws, 0, A_ZERO, stream);
    k_hist<<<512, 256, 0, stream>>>(attr, edst, hist, degi);
    k_scan<<<1, 1024, 0, stream>>>(degi, noff);
    k_scatterA<<<512, 256, 0, stream>>>(attr, edst, hist, cursors, ncur, noff, sorted, by_dst);
    k_edge_mfma_st<<<NTILES / 4, 256, 0, stream>>>(x, esrc, attr, weight, sorted, msgs);
    k_nodeA<<<(NN + 7) / 8, 256, 0, stream>>>(x, msgs, by_dst, noff, root, bias, out, gsum, gsumsq);
    k_bn<<<(NN * COUT) / 256, 256, 0, stream>>>(out, gsum, gsumsq, gamma, beta);
  } else {
    // -------- Path B: R4 fallback (atomic aggregation) --------
    float* agg     = (float*)(ws + B_AGG);
    int*   degi    = (int*)(ws + B_DEG);
    int*   hist    = (int*)(ws + B_HIST);
    int*   cursors = (int*)(ws + B_CUR);
    float* gsum    = (float*)(ws + B_SUM);
    float* gsumsq  = (float*)(ws + B_SUMSQ);
    int*   offsets = (int*)(ws + B_OFFS);
    int*   sorted  = (int*)(ws + B_SORT);

    hipMemsetAsync(ws, 0, B_ZERO, stream);
    k_hist<<<512, 256, 0, stream>>>(attr, edst, hist, degi);
    k_prefixB<<<1, 64, 0, stream>>>(hist, offsets);
    k_scatterB<<<512, 256, 0, stream>>>(attr, offsets, cursors, sorted);
    k_edge_atomic<<<NTILES / 4, 256, 0, stream>>>(x, esrc, edst, attr, weight, sorted, agg);
    k_nodeB<<<(NN + 31) / 32, 1024, 0, stream>>>(x, agg, degi, root, bias, out, gsum, gsumsq);
    k_bn<<<(NN * COUT) / 256, 256, 0, stream>>>(out, gsum, gsumsq, gamma, beta);
  }
}

// Round 6
// 253.780 us; speedup vs baseline: 1.0120x; 1.0120x over previous
//
#include <hip/hip_runtime.h>

#define NN 50000
#define EE 400000
#define CIN 16
#define COUT 32
#define NTILES (EE / 32)

typedef float f32x4  __attribute__((ext_vector_type(4)));
typedef float f32x16 __attribute__((ext_vector_type(16)));
typedef short short8 __attribute__((ext_vector_type(8)));

// ---- workspace layout (bytes); total ~55 MB (proven available in R5) ----
#define A_DEG    0                         // int degi[NN]
#define A_NCUR   200000                    // int node_cur[NN]
#define A_HIST   400000                    // int hist[64]
#define A_CUR    400256                    // int cursors[64]
#define A_SUM    400512                    // float gsum[32]
#define A_SUMSQ  400640                    // float gsumsq[32]
#define A_ZERO   400768                    // memset range [0, A_ZERO)
#define A_NOFF   400768                    // int node_off[NN+1]
#define A_SORT   (A_NOFF + 200064)         // int sorted[EE]   (cell-sorted edge ids)
#define A_CPOS   (A_SORT + 1600000)        // int cpos[EE]     (dst-CSR position by sorted slot)
#define A_MSG    (A_CPOS + 1600000)        // float msgs[EE*COUT] in dst-CSR order

__device__ __forceinline__ void cell_of(float a0, float a1, float a2,
                                        int& l0, int& l1, int& l2,
                                        float& f0, float& f1, float& f2) {
  float v0 = a0 * 4.0f, v1 = a1 * 4.0f, v2 = a2 * 4.0f;
  l0 = min(max((int)v0, 0), 3);
  l1 = min(max((int)v1, 0), 3);
  l2 = min(max((int)v2, 0), 3);
  f0 = v0 - (float)l0; f1 = v1 - (float)l1; f2 = v2 - (float)l2;
}

// K1: per-cell histogram + in-degree
__global__ void k_hist(const float* __restrict__ attr, const int* __restrict__ edst,
                       int* __restrict__ hist, int* __restrict__ degi) {
  __shared__ int lh[64];
  if (threadIdx.x < 64) lh[threadIdx.x] = 0;
  __syncthreads();
  for (int e = blockIdx.x * blockDim.x + threadIdx.x; e < EE; e += gridDim.x * blockDim.x) {
    int l0, l1, l2; float f0, f1, f2;
    cell_of(attr[e*3], attr[e*3+1], attr[e*3+2], l0, l1, l2, f0, f1, f2);
    atomicAdd(&lh[l0 | (l1 << 2) | (l2 << 4)], 1);
    atomicAdd(&degi[edst[e]], 1);
  }
  __syncthreads();
  if (threadIdx.x < 64 && lh[threadIdx.x]) atomicAdd(&hist[threadIdx.x], lh[threadIdx.x]);
}

// K2: 50k prefix scan of degi -> node_off (single block)
__global__ __launch_bounds__(1024) void k_scan(const int* __restrict__ degi,
                                               int* __restrict__ node_off) {
  __shared__ int part[1024];
  int t = threadIdx.x;
  const int CH = 49;  // 1024*49 >= 50000
  int b = t * CH, e = min(b + CH, NN);
  int s = 0;
  for (int i = b; i < e; ++i) s += degi[i];
  part[t] = s;
  __syncthreads();
  for (int d = 1; d < 1024; d <<= 1) {
    int v = (t >= d) ? part[t - d] : 0;
    __syncthreads();
    part[t] += v;
    __syncthreads();
  }
  int run = part[t] - s;  // exclusive base for this chunk
  for (int i = b; i < e; ++i) { node_off[i] = run; run += degi[i]; }
  if (t == 1023) node_off[NN] = part[1023];
}

// K3: scatter into cell buckets + record each sorted slot's dst-CSR position
__global__ void k_scatter(const float* __restrict__ attr, const int* __restrict__ edst,
                          const int* __restrict__ hist, int* __restrict__ cursors,
                          int* __restrict__ node_cur, const int* __restrict__ node_off,
                          int* __restrict__ sorted, int* __restrict__ cpos) {
  __shared__ int lcnt[64], lbase[64], lcur[64], coff[64];
  int tid = threadIdx.x;
  if (tid < 64) { lcnt[tid] = 0; lcur[tid] = 0; }
  if (tid == 0) { int r = 0; for (int c = 0; c < 64; ++c) { coff[c] = r; r += hist[c]; } }
  __syncthreads();
  int per = (EE + gridDim.x - 1) / gridDim.x;
  int b0 = blockIdx.x * per;
  int b1 = min(b0 + per, EE);
  for (int e = b0 + tid; e < b1; e += blockDim.x) {
    int l0, l1, l2; float f0, f1, f2;
    cell_of(attr[e*3], attr[e*3+1], attr[e*3+2], l0, l1, l2, f0, f1, f2);
    atomicAdd(&lcnt[l0 | (l1 << 2) | (l2 << 4)], 1);
  }
  __syncthreads();
  if (tid < 64 && lcnt[tid]) lbase[tid] = coff[tid] + atomicAdd(&cursors[tid], lcnt[tid]);
  __syncthreads();
  for (int e = b0 + tid; e < b1; e += blockDim.x) {
    int l0, l1, l2; float f0, f1, f2;
    cell_of(attr[e*3], attr[e*3+1], attr[e*3+2], l0, l1, l2, f0, f1, f2);
    int c = l0 | (l1 << 2) | (l2 << 4);
    int q = lbase[c] + atomicAdd(&lcur[c], 1);
    sorted[q] = e;
    int d = edst[e];
    int pos = node_off[d] + atomicAdd(&node_cur[d], 1);
    cpos[q] = pos;
  }
}

// K4: MFMA edge kernel, operand-swapped, scatter-store to dst-CSR position.
// A = weight frag (lane&31 = output channel), B = edge frag (lane&31 = edge).
// Lane holds 16 outputs of ITS OWN edge; stores 4x f32x4, each store instr
// covering one full 32B sector of the destination row (2 half-lanes/row).
// NO float atomics anywhere.
__global__ __launch_bounds__(256) void k_edge_st(
    const float* __restrict__ x, const int* __restrict__ esrc,
    const float* __restrict__ attr, const float* __restrict__ weight,
    const int* __restrict__ sorted, const int* __restrict__ cpos,
    float* __restrict__ msgs) {
  int gwave = (int)((blockIdx.x * blockDim.x + threadIdx.x) >> 6);
  if (gwave >= NTILES) return;
  int lane = threadIdx.x & 63;
  int col = lane & 31;
  int half = lane >> 5;

  int p = gwave * 32 + col;
  int e = sorted[p];
  int pos = cpos[p];
  float a0 = attr[e*3+0], a1 = attr[e*3+1], a2 = attr[e*3+2];
  int src = esrc[e];

  float v0 = a0 * 4.0f, v1 = a1 * 4.0f, v2 = a2 * 4.0f;
  int l0 = min(max((int)v0, 0), 3);
  int l1 = min(max((int)v1, 0), 3);
  int l2 = min(max((int)v2, 0), 3);
  float f0 = v0 - (float)l0, f1 = v1 - (float)l1, f2 = v2 - (float)l2;
  int mycell = l0 | (l1 << 2) | (l2 << 4);

  const float* xp = x + src * CIN + half * 8;
  float xs[8];
  {
    f32x4 xa = *(const f32x4*)xp;
    f32x4 xb = *(const f32x4*)(xp + 4);
#pragma unroll
    for (int j = 0; j < 4; ++j) { xs[j] = xa[j]; xs[j + 4] = xb[j]; }
  }

  int c_first = __builtin_amdgcn_readfirstlane(mycell);
  int c_last  = __builtin_amdgcn_readfirstlane(__shfl(mycell, 31, 64));
  int npass = (c_first == c_last) ? 1 : 2;

  f32x16 acc;
#pragma unroll
  for (int r = 0; r < 16; ++r) acc[r] = 0.0f;

  float g0 = 1.0f - f0, g1 = 1.0f - f1, g2 = 1.0f - f2;

  for (int pass = 0; pass < npass; ++pass) {
    int cell = pass ? c_last : c_first;
    int c0 = cell & 3, c1 = (cell >> 2) & 3, c2 = cell >> 4;
    bool act = (mycell == cell);
#pragma unroll
    for (int cb = 0; cb < 8; ++cb) {
      float w = ((cb & 1) ? f0 : g0) * (((cb >> 1) & 1) ? f1 : g1) * (((cb >> 2) & 1) ? f2 : g2);
      w = act ? w : 0.0f;
      short8 ev;  // edge operand (w * xs) bf16
#pragma unroll
      for (int j = 0; j < 8; ++j)
        ev[j] = __builtin_bit_cast(short, (__bf16)(w * xs[j]));
      int wi = (c0 + (cb & 1)) + 5 * (c1 + ((cb >> 1) & 1)) + 25 * (c2 + (cb >> 2));
      const float* wp = weight + wi * (CIN * COUT) + (half * 8) * COUT + col;
      short8 wv;  // weight operand W[k][o], o = lane&31
#pragma unroll
      for (int j = 0; j < 8; ++j)
        wv[j] = __builtin_bit_cast(short, (__bf16)wp[j * COUT]);
      acc = __builtin_amdgcn_mfma_f32_32x32x16_bf16(wv, ev, acc, 0, 0, 0);
    }
  }

  // D layout: col(lane&31)=edge, row r -> o=(r&3)+8*(r>>2)+4*half
  float* mp = msgs + (size_t)pos * COUT + 4 * half;
#pragma unroll
  for (int g = 0; g < 4; ++g) {
    f32x4 v;
    v[0] = acc[4*g + 0]; v[1] = acc[4*g + 1]; v[2] = acc[4*g + 2]; v[3] = acc[4*g + 3];
    *(f32x4*)(mp + 8 * g) = v;
  }
}

// K5: streaming segment-sum (rows contiguous per node) + root + ELU + BN stats.
// Addresses are computed (no index loads, no dependent chains): unroll-4 with
// independent accumulators -> BW-bound.
__global__ __launch_bounds__(256) void k_node2(
    const float* __restrict__ x, const float* __restrict__ msgs,
    const int* __restrict__ node_off,
    const float* __restrict__ root, const float* __restrict__ bias,
    float* __restrict__ hout, float* __restrict__ gsum, float* __restrict__ gsumsq) {
  int tid = threadIdx.x;
  int o = tid & 31;
  int nl = tid >> 5;
  int n = blockIdx.x * 8 + nl;
  float s1 = 0.0f, s2 = 0.0f;
  if (n < NN) {
    int k0 = node_off[n], k1 = node_off[n + 1];
    int d = k1 - k0;
    const float* mp = msgs + (size_t)k0 * COUT + o;
    float a0 = 0.0f, a1 = 0.0f, a2 = 0.0f, a3 = 0.0f;
    int k = 0;
    for (; k + 4 <= d; k += 4) {
      a0 += mp[(size_t)(k + 0) * COUT];
      a1 += mp[(size_t)(k + 1) * COUT];
      a2 += mp[(size_t)(k + 2) * COUT];
      a3 += mp[(size_t)(k + 3) * COUT];
    }
    for (; k < d; ++k) a0 += mp[(size_t)k * COUT];
    float s = (a0 + a1) + (a2 + a3);
    float a = s / fmaxf((float)d, 1.0f);
    const float* xp = x + n * CIN;
    float r = 0.0f;
#pragma unroll
    for (int i = 0; i < CIN; ++i) r = fmaf(xp[i], root[i * COUT + o], r);
    float hv = a + r + bias[o];
    hv = hv > 0.0f ? hv : expm1f(hv);
    hout[n * COUT + o] = hv;
    s1 = hv; s2 = hv * hv;
  }
  s1 += __shfl_xor(s1, 32);
  s2 += __shfl_xor(s2, 32);
  __shared__ float sred[2][4][32];
  int w = tid >> 6;
  if ((tid & 63) < 32) { sred[0][w][o] = s1; sred[1][w][o] = s2; }
  __syncthreads();
  if (tid < 32) {
    float t1 = 0.0f, t2 = 0.0f;
#pragma unroll
    for (int w2 = 0; w2 < 4; ++w2) { t1 += sred[0][w2][o]; t2 += sred[1][w2][o]; }
    atomicAdd(&gsum[o], t1);
    atomicAdd(&gsumsq[o], t2);
  }
}

// K6: finalize BatchNorm in-place
__global__ void k_bn(float* __restrict__ out, const float* __restrict__ gsum,
                     const float* __restrict__ gsumsq, const float* __restrict__ gamma,
                     const float* __restrict__ beta) {
  int idx = blockIdx.x * blockDim.x + threadIdx.x;
  if (idx >= NN * COUT) return;
  int o = idx & 31;
  float m = gsum[o] * (1.0f / NN);
  float var = gsumsq[o] * (1.0f / NN) - m * m;
  float inv = rsqrtf(var + 1e-5f);
  out[idx] = (out[idx] - m) * inv * gamma[o] + beta[o];
}

extern "C" void kernel_launch(void* const* d_in, const int* in_sizes, int n_in,
                              void* d_out, int out_size, void* d_ws, size_t ws_size,
                              hipStream_t stream) {
  const float* x      = (const float*)d_in[0];
  const int*   ei     = (const int*)d_in[1];
  const float* attr   = (const float*)d_in[2];
  const float* weight = (const float*)d_in[3];
  const float* root   = (const float*)d_in[4];
  const float* bias   = (const float*)d_in[5];
  const float* gamma  = (const float*)d_in[6];
  const float* beta   = (const float*)d_in[7];
  float* out = (float*)d_out;
  char* ws = (char*)d_ws;
  const int* esrc = ei;
  const int* edst = ei + EE;

  int*   degi    = (int*)(ws + A_DEG);
  int*   ncur    = (int*)(ws + A_NCUR);
  int*   hist    = (int*)(ws + A_HIST);
  int*   cursors = (int*)(ws + A_CUR);
  float* gsum    = (float*)(ws + A_SUM);
  float* gsumsq  = (float*)(ws + A_SUMSQ);
  int*   noff    = (int*)(ws + A_NOFF);
  int*   sorted  = (int*)(ws + A_SORT);
  int*   cpos    = (int*)(ws + A_CPOS);
  float* msgs    = (float*)(ws + A_MSG);

  hipMemsetAsync(ws, 0, A_ZERO, stream);
  k_hist<<<512, 256, 0, stream>>>(attr, edst, hist, degi);
  k_scan<<<1, 1024, 0, stream>>>(degi, noff);
  k_scatter<<<512, 256, 0, stream>>>(attr, edst, hist, cursors, ncur, noff, sorted, cpos);
  k_edge_st<<<NTILES / 4, 256, 0, stream>>>(x, esrc, attr, weight, sorted, cpos, msgs);
  k_node2<<<(NN + 7) / 8, 256, 0, stream>>>(x, msgs, noff, root, bias, out, gsum, gsumsq);
  k_bn<<<(NN * COUT) / 256, 256, 0, stream>>>(out, gsum, gsumsq, gamma, beta);
}

// Round 7
// 238.551 us; speedup vs baseline: 1.0766x; 1.0638x over previous
//
#include <hip/hip_runtime.h>

#define NN 50000
#define EE 400000
#define CIN 16
#define COUT 32
#define NTILES (EE / 32)

typedef float f32x4  __attribute__((ext_vector_type(4)));
typedef float f32x16 __attribute__((ext_vector_type(16)));
typedef short short8 __attribute__((ext_vector_type(8)));

// ---- workspace layout (bytes) ----
#define W_AGG   0                      // bf16 agg[NN*COUT] = 3.2 MB
#define W_DEG   (NN*COUT*2)            // int degi[NN]
#define W_HIST  (W_DEG + NN*4)         // int hist[64]
#define W_CUR   (W_HIST + 256)         // int cursors[64]
#define W_SUM   (W_CUR + 256)          // float gsum[32]
#define W_SUMSQ (W_SUM + 128)          // float gsumsq[32]
#define W_ZERO  (W_SUMSQ + 128)        // memset range [0, W_ZERO)
#define W_OFFS  W_ZERO                 // int offsets[65] (pad 512)
#define W_SORT  (W_OFFS + 512)         // int sorted[EE]

__device__ __forceinline__ void cell_of(float a0, float a1, float a2,
                                        int& l0, int& l1, int& l2,
                                        float& f0, float& f1, float& f2) {
  float v0 = a0 * 4.0f, v1 = a1 * 4.0f, v2 = a2 * 4.0f;
  l0 = min(max((int)v0, 0), 3);
  l1 = min(max((int)v1, 0), 3);
  l2 = min(max((int)v2, 0), 3);
  f0 = v0 - (float)l0; f1 = v1 - (float)l1; f2 = v2 - (float)l2;
}

// K1: per-cell histogram + in-degree
__global__ void k_hist(const float* __restrict__ attr, const int* __restrict__ edst,
                       int* __restrict__ hist, int* __restrict__ degi) {
  __shared__ int lh[64];
  if (threadIdx.x < 64) lh[threadIdx.x] = 0;
  __syncthreads();
  for (int e = blockIdx.x * blockDim.x + threadIdx.x; e < EE; e += gridDim.x * blockDim.x) {
    int l0, l1, l2; float f0, f1, f2;
    cell_of(attr[e*3], attr[e*3+1], attr[e*3+2], l0, l1, l2, f0, f1, f2);
    atomicAdd(&lh[l0 | (l1 << 2) | (l2 << 4)], 1);
    atomicAdd(&degi[edst[e]], 1);
  }
  __syncthreads();
  if (threadIdx.x < 64 && lh[threadIdx.x]) atomicAdd(&hist[threadIdx.x], lh[threadIdx.x]);
}

// K2: serial prefix over 64 bins
__global__ void k_prefix(const int* __restrict__ hist, int* __restrict__ offsets) {
  if (threadIdx.x == 0) {
    int r = 0;
    for (int c = 0; c < 64; ++c) { offsets[c] = r; r += hist[c]; }
    offsets[64] = r;
  }
}

// K3: two-level scatter into cell buckets
__global__ void k_scatter(const float* __restrict__ attr, const int* __restrict__ offsets,
                          int* __restrict__ cursors, int* __restrict__ sorted) {
  __shared__ int lcnt[64], lbase[64], lcur[64];
  int tid = threadIdx.x;
  if (tid < 64) { lcnt[tid] = 0; lcur[tid] = 0; }
  __syncthreads();
  int per = (EE + gridDim.x - 1) / gridDim.x;
  int b0 = blockIdx.x * per;
  int b1 = min(b0 + per, EE);
  for (int e = b0 + tid; e < b1; e += blockDim.x) {
    int l0, l1, l2; float f0, f1, f2;
    cell_of(attr[e*3], attr[e*3+1], attr[e*3+2], l0, l1, l2, f0, f1, f2);
    atomicAdd(&lcnt[l0 | (l1 << 2) | (l2 << 4)], 1);
  }
  __syncthreads();
  if (tid < 64 && lcnt[tid]) lbase[tid] = offsets[tid] + atomicAdd(&cursors[tid], lcnt[tid]);
  __syncthreads();
  for (int e = b0 + tid; e < b1; e += blockDim.x) {
    int l0, l1, l2; float f0, f1, f2;
    cell_of(attr[e*3], attr[e*3+1], attr[e*3+2], l0, l1, l2, f0, f1, f2);
    int c = l0 | (l1 << 2) | (l2 << 4);
    int p = atomicAdd(&lcur[c], 1);
    sorted[lbase[c] + p] = e;
  }
}

// K4: MFMA edge kernel, operand-swapped (lane owns all 32 channels of its own
// edge), aggregation via global_atomic_pk_add_bf16: 8 packed atomics per edge
// (2 channels each) instead of 16 f32 atomics + 16 shfls. agg is bf16 (3.2 MB,
// L2-resident RMWs).
__global__ __launch_bounds__(256) void k_edge_pk(
    const float* __restrict__ x, const int* __restrict__ esrc, const int* __restrict__ edst,
    const float* __restrict__ attr, const float* __restrict__ weight,
    const int* __restrict__ sorted, unsigned short* __restrict__ agg) {
  int gwave = (int)((blockIdx.x * blockDim.x + threadIdx.x) >> 6);
  if (gwave >= NTILES) return;
  int lane = threadIdx.x & 63;
  int col = lane & 31;
  int half = lane >> 5;

  int p = gwave * 32 + col;
  int e = sorted[p];
  float a0 = attr[e*3+0], a1 = attr[e*3+1], a2 = attr[e*3+2];
  int src = esrc[e];
  int dst = edst[e];

  float v0 = a0 * 4.0f, v1 = a1 * 4.0f, v2 = a2 * 4.0f;
  int l0 = min(max((int)v0, 0), 3);
  int l1 = min(max((int)v1, 0), 3);
  int l2 = min(max((int)v2, 0), 3);
  float f0 = v0 - (float)l0, f1 = v1 - (float)l1, f2 = v2 - (float)l2;
  int mycell = l0 | (l1 << 2) | (l2 << 4);

  const float* xp = x + src * CIN + half * 8;
  float xs[8];
  {
    f32x4 xa = *(const f32x4*)xp;
    f32x4 xb = *(const f32x4*)(xp + 4);
#pragma unroll
    for (int j = 0; j < 4; ++j) { xs[j] = xa[j]; xs[j + 4] = xb[j]; }
  }

  int c_first = __builtin_amdgcn_readfirstlane(mycell);
  int c_last  = __builtin_amdgcn_readfirstlane(__shfl(mycell, 31, 64));
  int npass = (c_first == c_last) ? 1 : 2;

  f32x16 acc;
#pragma unroll
  for (int r = 0; r < 16; ++r) acc[r] = 0.0f;

  float g0 = 1.0f - f0, g1 = 1.0f - f1, g2 = 1.0f - f2;

  for (int pass = 0; pass < npass; ++pass) {
    int cell = pass ? c_last : c_first;
    int c0 = cell & 3, c1 = (cell >> 2) & 3, c2 = cell >> 4;
    bool act = (mycell == cell);
#pragma unroll
    for (int cb = 0; cb < 8; ++cb) {
      float w = ((cb & 1) ? f0 : g0) * (((cb >> 1) & 1) ? f1 : g1) * (((cb >> 2) & 1) ? f2 : g2);
      w = act ? w : 0.0f;
      short8 ev;  // edge operand (w * xs) bf16
#pragma unroll
      for (int j = 0; j < 8; ++j)
        ev[j] = __builtin_bit_cast(short, (__bf16)(w * xs[j]));
      int wi = (c0 + (cb & 1)) + 5 * (c1 + ((cb >> 1) & 1)) + 25 * (c2 + (cb >> 2));
      const float* wp = weight + wi * (CIN * COUT) + (half * 8) * COUT + col;
      short8 wv;  // weight operand W[k][o]
#pragma unroll
      for (int j = 0; j < 8; ++j)
        wv[j] = __builtin_bit_cast(short, (__bf16)wp[j * COUT]);
      // swapped: weights as A, edges as B -> D[o][edge]
      acc = __builtin_amdgcn_mfma_f32_32x32x16_bf16(wv, ev, acc, 0, 0, 0);
    }
  }

  // D layout: col(lane&31)=edge, row r -> channel o=(r&3)+8*(r>>2)+4*half.
  // Per g: channels {8g+4h+0, 8g+4h+1} = (acc[4g],acc[4g+1]) and
  //        {8g+4h+2, 8g+4h+3} = (acc[4g+2],acc[4g+3]) -> two pk atomics.
  unsigned long long base = (unsigned long long)(agg + (size_t)dst * COUT + 4 * half);
#pragma unroll
  for (int g = 0; g < 4; ++g) {
    unsigned pk0 = ((unsigned)__builtin_bit_cast(unsigned short, (__bf16)acc[4*g + 1]) << 16)
                 |  (unsigned)__builtin_bit_cast(unsigned short, (__bf16)acc[4*g + 0]);
    unsigned pk1 = ((unsigned)__builtin_bit_cast(unsigned short, (__bf16)acc[4*g + 3]) << 16)
                 |  (unsigned)__builtin_bit_cast(unsigned short, (__bf16)acc[4*g + 2]);
    unsigned long long p0 = base + (unsigned long long)(16 * g);
    asm volatile("global_atomic_pk_add_bf16 %0, %1, off" :: "v"(p0), "v"(pk0) : "memory");
    asm volatile("global_atomic_pk_add_bf16 %0, %1, off" :: "v"(p0 + 4), "v"(pk1) : "memory");
  }
}

// K5: node kernel, grid-stride (256 blocks): bf16 agg read, mean, x@root+bias,
// ELU, write h, BN partial sums accumulated in registers across the stride ->
// only 256*64 gsum RMWs total.
__global__ __launch_bounds__(1024) void k_node(
    const float* __restrict__ x, const unsigned short* __restrict__ agg,
    const int* __restrict__ degi,
    const float* __restrict__ root, const float* __restrict__ bias,
    float* __restrict__ hout, float* __restrict__ gsum, float* __restrict__ gsumsq) {
  int tid = threadIdx.x;
  int o = tid & 31;
  int nl = tid >> 5;                 // node-in-tile, 0..31
  float s1 = 0.0f, s2 = 0.0f;
  const int NTILE = (NN + 31) / 32;  // 1563
  for (int t = blockIdx.x; t < NTILE; t += gridDim.x) {
    int n = t * 32 + nl;
    if (n < NN) {
      unsigned short raw = agg[n * COUT + o];
      float a = (float)__builtin_bit_cast(__bf16, raw);
      a /= fmaxf((float)degi[n], 1.0f);
      const float* xp = x + n * CIN;
      float r = 0.0f;
#pragma unroll
      for (int i = 0; i < CIN; ++i) r = fmaf(xp[i], root[i * COUT + o], r);
      float hv = a + r + bias[o];
      hv = hv > 0.0f ? hv : expm1f(hv);
      hout[n * COUT + o] = hv;
      s1 += hv; s2 += hv * hv;
    }
  }
  s1 += __shfl_xor(s1, 32);
  s2 += __shfl_xor(s2, 32);
  __shared__ float sred[2][16][32];
  int w = tid >> 6;
  if ((tid & 63) < 32) { sred[0][w][o] = s1; sred[1][w][o] = s2; }
  __syncthreads();
  if (tid < 32) {
    float t1 = 0.0f, t2 = 0.0f;
#pragma unroll
    for (int w2 = 0; w2 < 16; ++w2) { t1 += sred[0][w2][o]; t2 += sred[1][w2][o]; }
    atomicAdd(&gsum[o], t1);
    atomicAdd(&gsumsq[o], t2);
  }
}

// K6: finalize BatchNorm in-place
__global__ void k_bn(float* __restrict__ out, const float* __restrict__ gsum,
                     const float* __restrict__ gsumsq, const float* __restrict__ gamma,
                     const float* __restrict__ beta) {
  int idx = blockIdx.x * blockDim.x + threadIdx.x;
  if (idx >= NN * COUT) return;
  int o = idx & 31;
  float m = gsum[o] * (1.0f / NN);
  float var = gsumsq[o] * (1.0f / NN) - m * m;
  float inv = rsqrtf(var + 1e-5f);
  out[idx] = (out[idx] - m) * inv * gamma[o] + beta[o];
}

extern "C" void kernel_launch(void* const* d_in, const int* in_sizes, int n_in,
                              void* d_out, int out_size, void* d_ws, size_t ws_size,
                              hipStream_t stream) {
  const float* x      = (const float*)d_in[0];
  const int*   ei     = (const int*)d_in[1];
  const float* attr   = (const float*)d_in[2];
  const float* weight = (const float*)d_in[3];
  const float* root   = (const float*)d_in[4];
  const float* bias   = (const float*)d_in[5];
  const float* gamma  = (const float*)d_in[6];
  const float* beta   = (const float*)d_in[7];
  float* out = (float*)d_out;
  char* ws = (char*)d_ws;
  const int* esrc = ei;
  const int* edst = ei + EE;

  unsigned short* agg = (unsigned short*)(ws + W_AGG);
  int*   degi    = (int*)(ws + W_DEG);
  int*   hist    = (int*)(ws + W_HIST);
  int*   cursors = (int*)(ws + W_CUR);
  float* gsum    = (float*)(ws + W_SUM);
  float* gsumsq  = (float*)(ws + W_SUMSQ);
  int*   offsets = (int*)(ws + W_OFFS);
  int*   sorted  = (int*)(ws + W_SORT);

  hipMemsetAsync(ws, 0, W_ZERO, stream);   // bf16 +0 == 0x0000
  k_hist<<<512, 256, 0, stream>>>(attr, edst, hist, degi);
  k_prefix<<<1, 64, 0, stream>>>(hist, offsets);
  k_scatter<<<512, 256, 0, stream>>>(attr, offsets, cursors, sorted);
  k_edge_pk<<<NTILES / 4, 256, 0, stream>>>(x, esrc, edst, attr, weight, sorted, agg);
  k_node<<<256, 1024, 0, stream>>>(x, agg, degi, root, bias, out, gsum, gsumsq);
  k_bn<<<(NN * COUT) / 256, 256, 0, stream>>>(out, gsum, gsumsq, gamma, beta);
}

// Round 8
// 237.393 us; speedup vs baseline: 1.0818x; 1.0049x over previous
//
#include <hip/hip_runtime.h>

#define NN 50000
#define EE 400000
#define CIN 16
#define COUT 32
#define NPB  66                    // nodes per dst-bucket
#define NBKT 758                   // ceil(50000/66)
#define NBINS (NBKT * 64)          // (bucket, cell) bins = 48512

typedef float f32x4  __attribute__((ext_vector_type(4)));
typedef float f32x16 __attribute__((ext_vector_type(16)));
typedef short short8 __attribute__((ext_vector_type(8)));

// ---- workspace layout (bytes) ----
#define W_HIST  0                          // int hist[NBINS]      194048
#define W_CURS  (W_HIST + NBINS*4)         // int cursors[NBINS]
#define W_DEG   (W_CURS + NBINS*4)         // int degi[NN]
#define W_SUM   (W_DEG + NN*4)             // float gsum[32]
#define W_SUMSQ (W_SUM + 128)              // float gsumsq[32]
#define W_ZERO  (W_SUMSQ + 128)            // memset range [0, W_ZERO)
#define W_OFFS  W_ZERO                     // int offsets[NBINS+1] (pad)
#define W_SORT  (W_OFFS + (NBINS+1)*4 + 60) // int sorted[EE]

__device__ __forceinline__ int cell_and_frac(float a0, float a1, float a2,
                                             float& f0, float& f1, float& f2) {
  float v0 = a0 * 4.0f, v1 = a1 * 4.0f, v2 = a2 * 4.0f;
  int l0 = min(max((int)v0, 0), 3);
  int l1 = min(max((int)v1, 0), 3);
  int l2 = min(max((int)v2, 0), 3);
  f0 = v0 - (float)l0; f1 = v1 - (float)l1; f2 = v2 - (float)l2;
  return l0 | (l1 << 2) | (l2 << 4);
}

// K1: (bucket,cell)-bin histogram + in-degree (direct global atomics)
__global__ void k_hist(const float* __restrict__ attr, const int* __restrict__ edst,
                       int* __restrict__ hist, int* __restrict__ degi) {
  for (int e = blockIdx.x * blockDim.x + threadIdx.x; e < EE; e += gridDim.x * blockDim.x) {
    float f0, f1, f2;
    int cell = cell_and_frac(attr[e*3], attr[e*3+1], attr[e*3+2], f0, f1, f2);
    int d = edst[e];
    int bin = (d / NPB) * 64 + cell;
    atomicAdd(&hist[bin], 1);
    atomicAdd(&degi[d], 1);
  }
}

// K2: prefix scan over NBINS bins (single block, 1024 threads x 48 bins)
__global__ __launch_bounds__(1024) void k_scan(const int* __restrict__ hist,
                                               int* __restrict__ offsets) {
  __shared__ int part[1024];
  int t = threadIdx.x;
  const int CH = 48;  // 1024*48 = 49152 >= 48512
  int b = t * CH, e = min(b + CH, NBINS);
  int s = 0;
  for (int i = b; i < e; ++i) s += hist[i];
  part[t] = s;
  __syncthreads();
  for (int d = 1; d < 1024; d <<= 1) {
    int v = (t >= d) ? part[t - d] : 0;
    __syncthreads();
    part[t] += v;
    __syncthreads();
  }
  int run = part[t] - s;  // exclusive base
  for (int i = b; i < e; ++i) { offsets[i] = run; run += hist[i]; }
  if (t == 1023) offsets[NBINS] = part[1023];
}

// K3: scatter edges into (bucket,cell) bins
__global__ void k_scatter(const float* __restrict__ attr, const int* __restrict__ edst,
                          const int* __restrict__ offsets, int* __restrict__ cursors,
                          int* __restrict__ sorted) {
  for (int e = blockIdx.x * blockDim.x + threadIdx.x; e < EE; e += gridDim.x * blockDim.x) {
    float f0, f1, f2;
    int cell = cell_and_frac(attr[e*3], attr[e*3+1], attr[e*3+2], f0, f1, f2);
    int bin = (edst[e] / NPB) * 64 + cell;
    int q = offsets[bin] + atomicAdd(&cursors[bin], 1);
    sorted[q] = e;
  }
}

// K4: mega kernel. One block (4 waves) per dst-bucket (~528 edges, 66 nodes).
// Edges within the bucket are cell-sorted; a wave takes a 32-edge tile and
// runs the swapped-operand MFMA (lane owns all 32 channels of its own edge)
// once per DISTINCT cell in the tile (ballot/ffs multi-pass, inactive edges
// masked to w=0). Results merge via ds_add_f32 into a 66x32 f32 LDS tile
// (channel rotated by +ldst to spread banks). Node phase (mean, x@root, ELU,
// BN partials) runs from LDS in the same block. Zero global float atomics.
__global__ __launch_bounds__(256) void k_mega(
    const float* __restrict__ x, const int* __restrict__ esrc, const int* __restrict__ edst,
    const float* __restrict__ attr, const float* __restrict__ weight,
    const int* __restrict__ sorted, const int* __restrict__ offsets,
    const int* __restrict__ degi, const float* __restrict__ root,
    const float* __restrict__ bias, float* __restrict__ out,
    float* __restrict__ gsum, float* __restrict__ gsumsq) {
  __shared__ float lagg[NPB * 32];
  __shared__ float sred[2][4][32];
  int bkt = blockIdx.x;
  int tid = threadIdx.x;
  for (int i = tid; i < NPB * 32; i += 256) lagg[i] = 0.0f;
  __syncthreads();

  int s = offsets[bkt * 64];
  int t = offsets[(bkt + 1) * 64];
  int lane = tid & 63;
  int col = lane & 31;
  int half = lane >> 5;
  int wv = tid >> 6;

  int nt = (t - s + 31) >> 5;
  for (int ti = wv; ti < nt; ti += 4) {
    int p = s + ti * 32 + col;
    bool valid = p < t;
    int e = sorted[valid ? p : (t - 1)];
    float a0 = attr[e*3+0], a1 = attr[e*3+1], a2 = attr[e*3+2];
    int src = esrc[e];
    int dst = edst[e];

    float f0, f1, f2;
    int mycell = cell_and_frac(a0, a1, a2, f0, f1, f2);
    float g0 = 1.0f - f0, g1 = 1.0f - f1, g2 = 1.0f - f2;

    const float* xp = x + src * CIN + half * 8;
    float xs[8];
    {
      f32x4 xa = *(const f32x4*)xp;
      f32x4 xb = *(const f32x4*)(xp + 4);
#pragma unroll
      for (int j = 0; j < 4; ++j) { xs[j] = xa[j]; xs[j + 4] = xb[j]; }
    }

    f32x16 acc;
#pragma unroll
    for (int r = 0; r < 16; ++r) acc[r] = 0.0f;

    unsigned rem = (unsigned)(__ballot(valid) & 0xffffffffull);
    while (rem) {
      int slot = __ffs(rem) - 1;
      int cs = __builtin_amdgcn_readfirstlane(__shfl(mycell, slot, 64));
      unsigned long long bal = __ballot(valid && (mycell == cs));
      bool act = valid && (mycell == cs);
      int c0 = cs & 3, c1 = (cs >> 2) & 3, c2 = cs >> 4;
#pragma unroll
      for (int cb = 0; cb < 8; ++cb) {
        float w = ((cb & 1) ? f0 : g0) * (((cb >> 1) & 1) ? f1 : g1)
                * (((cb >> 2) & 1) ? f2 : g2);
        w = act ? w : 0.0f;
        short8 ev;  // edge operand (w * xs) bf16
#pragma unroll
        for (int j = 0; j < 8; ++j)
          ev[j] = __builtin_bit_cast(short, (__bf16)(w * xs[j]));
        int wi = (c0 + (cb & 1)) + 5 * (c1 + ((cb >> 1) & 1)) + 25 * (c2 + (cb >> 2));
        const float* wp = weight + wi * (CIN * COUT) + (half * 8) * COUT + col;
        short8 wvv;  // weight operand W[k][o], o = lane&31
#pragma unroll
        for (int j = 0; j < 8; ++j)
          wvv[j] = __builtin_bit_cast(short, (__bf16)wp[j * COUT]);
        acc = __builtin_amdgcn_mfma_f32_32x32x16_bf16(wvv, ev, acc, 0, 0, 0);
      }
      rem &= ~(unsigned)(bal & 0xffffffffull);
    }

    // merge into LDS: lane owns channels o=(r&3)+8*(r>>2)+4*half of its edge
    if (valid) {
      int ldst = dst - bkt * NPB;
#pragma unroll
      for (int r = 0; r < 16; ++r) {
        int o = (r & 3) + 8 * (r >> 2) + 4 * half;
        atomicAdd(&lagg[ldst * 32 + ((o + ldst) & 31)], acc[r]);
      }
    }
  }
  __syncthreads();

  // node phase from LDS
  float s1 = 0.0f, s2 = 0.0f;
  int o = tid & 31;
  for (int nl = tid >> 5; nl < NPB; nl += 8) {
    int n = bkt * NPB + nl;
    if (n < NN) {
      float a = lagg[nl * 32 + ((o + nl) & 31)] / fmaxf((float)degi[n], 1.0f);
      const float* xp = x + n * CIN;
      float r = 0.0f;
#pragma unroll
      for (int i = 0; i < CIN; ++i) r = fmaf(xp[i], root[i * COUT + o], r);
      float hv = a + r + bias[o];
      hv = hv > 0.0f ? hv : expm1f(hv);
      out[n * COUT + o] = hv;
      s1 += hv; s2 += hv * hv;
    }
  }
  s1 += __shfl_xor(s1, 32);
  s2 += __shfl_xor(s2, 32);
  int w = tid >> 6;
  if ((tid & 63) < 32) { sred[0][w][o] = s1; sred[1][w][o] = s2; }
  __syncthreads();
  if (tid < 32) {
    float t1 = 0.0f, t2 = 0.0f;
#pragma unroll
    for (int w2 = 0; w2 < 4; ++w2) { t1 += sred[0][w2][o]; t2 += sred[1][w2][o]; }
    atomicAdd(&gsum[o], t1);
    atomicAdd(&gsumsq[o], t2);
  }
}

// K5: finalize BatchNorm in-place
__global__ void k_bn(float* __restrict__ out, const float* __restrict__ gsum,
                     const float* __restrict__ gsumsq, const float* __restrict__ gamma,
                     const float* __restrict__ beta) {
  int idx = blockIdx.x * blockDim.x + threadIdx.x;
  if (idx >= NN * COUT) return;
  int o = idx & 31;
  float m = gsum[o] * (1.0f / NN);
  float var = gsumsq[o] * (1.0f / NN) - m * m;
  float inv = rsqrtf(var + 1e-5f);
  out[idx] = (out[idx] - m) * inv * gamma[o] + beta[o];
}

extern "C" void kernel_launch(void* const* d_in, const int* in_sizes, int n_in,
                              void* d_out, int out_size, void* d_ws, size_t ws_size,
                              hipStream_t stream) {
  const float* x      = (const float*)d_in[0];
  const int*   ei     = (const int*)d_in[1];
  const float* attr   = (const float*)d_in[2];
  const float* weight = (const float*)d_in[3];
  const float* root   = (const float*)d_in[4];
  const float* bias   = (const float*)d_in[5];
  const float* gamma  = (const float*)d_in[6];
  const float* beta   = (const float*)d_in[7];
  float* out = (float*)d_out;
  char* ws = (char*)d_ws;
  const int* esrc = ei;
  const int* edst = ei + EE;

  int*   hist    = (int*)(ws + W_HIST);
  int*   cursors = (int*)(ws + W_CURS);
  int*   degi    = (int*)(ws + W_DEG);
  float* gsum    = (float*)(ws + W_SUM);
  float* gsumsq  = (float*)(ws + W_SUMSQ);
  int*   offsets = (int*)(ws + W_OFFS);
  int*   sorted  = (int*)(ws + W_SORT);

  hipMemsetAsync(ws, 0, W_ZERO, stream);
  k_hist<<<512, 256, 0, stream>>>(attr, edst, hist, degi);
  k_scan<<<1, 1024, 0, stream>>>(hist, offsets);
  k_scatter<<<512, 256, 0, stream>>>(attr, edst, offsets, cursors, sorted);
  k_mega<<<NBKT, 256, 0, stream>>>(x, esrc, edst, attr, weight, sorted, offsets,
                                   degi, root, bias, out, gsum, gsumsq);
  k_bn<<<(NN * COUT) / 256, 256, 0, stream>>>(out, gsum, gsumsq, gamma, beta);
}

// Round 10
// 237.096 us; speedup vs baseline: 1.0832x; 1.0012x over previous
//
#include <hip/hip_runtime.h>

#define NN 50000
#define EE 400000
#define CIN 16
#define COUT 32
#define NPB  66                    // nodes per dst-bucket
#define NBKT 758                   // ceil(50000/66)
#define NBINS (NBKT * 64)          // (bucket, cell) bins

typedef float f32x4  __attribute__((ext_vector_type(4)));
typedef float f32x16 __attribute__((ext_vector_type(16)));
typedef short short8 __attribute__((ext_vector_type(8)));

// ---- workspace layout (bytes) ----
#define W_HIST  0                           // int hist[NBINS]
#define W_CURS  (W_HIST + NBINS*4)          // int cursors[NBINS]
#define W_DEG   (W_CURS + NBINS*4)          // int degi[NN]
#define W_SUM   (W_DEG + NN*4)              // float gsum[32]
#define W_SUMSQ (W_SUM + 128)               // float gsumsq[32]
#define W_ZERO  (W_SUMSQ + 128)             // memset range [0, W_ZERO)
#define W_OFFS  W_ZERO                      // int offsets[NBINS+1]
#define W_SORT  (W_OFFS + (NBINS+1)*4 + 60) // int sorted[EE]
#define W_WBF   (W_SORT + EE*4)             // bf16 wbf[125][2][32][8] = 128 KB

__device__ __forceinline__ int cell_and_frac(float a0, float a1, float a2,
                                             float& f0, float& f1, float& f2) {
  float v0 = a0 * 4.0f, v1 = a1 * 4.0f, v2 = a2 * 4.0f;
  int l0 = min(max((int)v0, 0), 3);
  int l1 = min(max((int)v1, 0), 3);
  int l2 = min(max((int)v2, 0), 3);
  f0 = v0 - (float)l0; f1 = v1 - (float)l1; f2 = v2 - (float)l2;
  return l0 | (l1 << 2) | (l2 << 4);
}

// K0: weight f32 -> bf16 MFMA-fragment layout, GATHER form: thread = output
// ushort position pos = ((wi*2+half)*32 + o)*8 + j, reads weight[wi][half*8+j][o].
// (Read side in k_mega uses exactly pos with o=col -> mapping trivially inverse.)
__global__ void k_wconv(const float* __restrict__ w, unsigned short* __restrict__ wbf) {
  int pos = blockIdx.x * blockDim.x + threadIdx.x;
  if (pos >= 125 * CIN * COUT) return;
  int j    = pos & 7;
  int o    = (pos >> 3) & 31;
  int wh   = pos >> 8;          // wi*2 + half
  int wi   = wh >> 1;
  int half = wh & 1;
  int k    = half * 8 + j;
  wbf[pos] = __builtin_bit_cast(unsigned short, (__bf16)w[wi * (CIN * COUT) + k * COUT + o]);
}

// K1: (bucket,cell)-bin histogram + in-degree (proven R8)
__global__ void k_hist(const float* __restrict__ attr, const int* __restrict__ edst,
                       int* __restrict__ hist, int* __restrict__ degi) {
  for (int e = blockIdx.x * blockDim.x + threadIdx.x; e < EE; e += gridDim.x * blockDim.x) {
    float f0, f1, f2;
    int cell = cell_and_frac(attr[e*3], attr[e*3+1], attr[e*3+2], f0, f1, f2);
    int d = edst[e];
    atomicAdd(&hist[(d / NPB) * 64 + cell], 1);
    atomicAdd(&degi[d], 1);
  }
}

// K2: prefix scan over NBINS bins (proven R8)
__global__ __launch_bounds__(1024) void k_scan(const int* __restrict__ hist,
                                               int* __restrict__ offsets) {
  __shared__ int part[1024];
  int t = threadIdx.x;
  const int CH = 48;
  int b = t * CH, e = min(b + CH, NBINS);
  int s = 0;
  for (int i = b; i < e; ++i) s += hist[i];
  part[t] = s;
  __syncthreads();
  for (int d = 1; d < 1024; d <<= 1) {
    int v = (t >= d) ? part[t - d] : 0;
    __syncthreads();
    part[t] += v;
    __syncthreads();
  }
  int run = part[t] - s;
  for (int i = b; i < e; ++i) { offsets[i] = run; run += hist[i]; }
  if (t == 1023) offsets[NBINS] = part[1023];
}

// K3: scatter edges into (bucket,cell) bins (proven R8)
__global__ void k_scatter(const float* __restrict__ attr, const int* __restrict__ edst,
                          const int* __restrict__ offsets, int* __restrict__ cursors,
                          int* __restrict__ sorted) {
  for (int e = blockIdx.x * blockDim.x + threadIdx.x; e < EE; e += gridDim.x * blockDim.x) {
    float f0, f1, f2;
    int cell = cell_and_frac(attr[e*3], attr[e*3+1], attr[e*3+2], f0, f1, f2);
    int bin = (edst[e] / NPB) * 64 + cell;
    int q = offsets[bin] + atomicAdd(&cursors[bin], 1);
    sorted[q] = e;
  }
}

// K4: mega kernel — R8 structure (proven), now 8 waves/block (occupancy fix)
// and weight operand as ONE 16B bf16 fragment load from wbf (per-pass VALU fix).
__global__ __launch_bounds__(512) void k_mega(
    const float* __restrict__ x, const int* __restrict__ esrc, const int* __restrict__ edst,
    const float* __restrict__ attr, const unsigned short* __restrict__ wbf,
    const int* __restrict__ sorted, const int* __restrict__ offsets,
    const int* __restrict__ degi, const float* __restrict__ root,
    const float* __restrict__ bias, float* __restrict__ out,
    float* __restrict__ gsum, float* __restrict__ gsumsq) {
  __shared__ float lagg[NPB * 32];
  __shared__ float sred[2][8][32];
  int bkt = blockIdx.x;
  int tid = threadIdx.x;
  for (int i = tid; i < NPB * 32; i += 512) lagg[i] = 0.0f;
  __syncthreads();

  int s = offsets[bkt * 64];
  int t = offsets[(bkt + 1) * 64];
  int lane = tid & 63;
  int col = lane & 31;
  int half = lane >> 5;
  int wv = tid >> 6;

  int nt = (t - s + 31) >> 5;
  for (int ti = wv; ti < nt; ti += 8) {
    int p = s + ti * 32 + col;
    bool valid = p < t;
    int e = sorted[valid ? p : (t - 1)];
    float a0 = attr[e*3+0], a1 = attr[e*3+1], a2 = attr[e*3+2];
    int src = esrc[e];
    int dst = edst[e];

    float f0, f1, f2;
    int mycell = cell_and_frac(a0, a1, a2, f0, f1, f2);
    float g0 = 1.0f - f0, g1 = 1.0f - f1, g2 = 1.0f - f2;

    const float* xp = x + src * CIN + half * 8;
    float xs[8];
    {
      f32x4 xa = *(const f32x4*)xp;
      f32x4 xb = *(const f32x4*)(xp + 4);
#pragma unroll
      for (int j = 0; j < 4; ++j) { xs[j] = xa[j]; xs[j + 4] = xb[j]; }
    }

    f32x16 acc;
#pragma unroll
    for (int r = 0; r < 16; ++r) acc[r] = 0.0f;

    unsigned rem = (unsigned)(__ballot(valid) & 0xffffffffull);
    while (rem) {
      int slot = __ffs(rem) - 1;
      int cs = __builtin_amdgcn_readfirstlane(__shfl(mycell, slot, 64));
      unsigned long long bal = __ballot(valid && (mycell == cs));
      bool act = valid && (mycell == cs);
      int c0 = cs & 3, c1 = (cs >> 2) & 3, c2 = cs >> 4;
#pragma unroll
      for (int cb = 0; cb < 8; ++cb) {
        float w = ((cb & 1) ? f0 : g0) * (((cb >> 1) & 1) ? f1 : g1)
                * (((cb >> 2) & 1) ? f2 : g2);
        w = act ? w : 0.0f;
        short8 ev;
#pragma unroll
        for (int j = 0; j < 8; ++j)
          ev[j] = __builtin_bit_cast(short, (__bf16)(w * xs[j]));
        int wi = (c0 + (cb & 1)) + 5 * (c1 + ((cb >> 1) & 1)) + 25 * (c2 + (cb >> 2));
        short8 wvv = *(const short8*)(wbf + (size_t)(((wi * 2 + half) * 32 + col) * 8));
        acc = __builtin_amdgcn_mfma_f32_32x32x16_bf16(wvv, ev, acc, 0, 0, 0);
      }
      rem &= ~(unsigned)(bal & 0xffffffffull);
    }

    if (valid) {
      int ldst = dst - bkt * NPB;
#pragma unroll
      for (int r = 0; r < 16; ++r) {
        int o = (r & 3) + 8 * (r >> 2) + 4 * half;
        atomicAdd(&lagg[ldst * 32 + ((o + ldst) & 31)], acc[r]);
      }
    }
  }
  __syncthreads();

  // node phase from LDS
  float s1 = 0.0f, s2 = 0.0f;
  int o = tid & 31;
  for (int nl = tid >> 5; nl < NPB; nl += 16) {
    int n = bkt * NPB + nl;
    if (n < NN) {
      float a = lagg[nl * 32 + ((o + nl) & 31)] / fmaxf((float)degi[n], 1.0f);
      const float* xp = x + n * CIN;
      float r = 0.0f;
#pragma unroll
      for (int i = 0; i < CIN; ++i) r = fmaf(xp[i], root[i * COUT + o], r);
      float hv = a + r + bias[o];
      hv = hv > 0.0f ? hv : expm1f(hv);
      out[n * COUT + o] = hv;
      s1 += hv; s2 += hv * hv;
    }
  }
  s1 += __shfl_xor(s1, 32);
  s2 += __shfl_xor(s2, 32);
  int w = tid >> 6;
  if ((tid & 63) < 32) { sred[0][w][o] = s1; sred[1][w][o] = s2; }
  __syncthreads();
  if (tid < 32) {
    float t1 = 0.0f, t2 = 0.0f;
#pragma unroll
    for (int w2 = 0; w2 < 8; ++w2) { t1 += sred[0][w2][o]; t2 += sred[1][w2][o]; }
    atomicAdd(&gsum[o], t1);
    atomicAdd(&gsumsq[o], t2);
  }
}

// K5: finalize BatchNorm in-place
__global__ void k_bn(float* __restrict__ out, const float* __restrict__ gsum,
                     const float* __restrict__ gsumsq, const float* __restrict__ gamma,
                     const float* __restrict__ beta) {
  int idx = blockIdx.x * blockDim.x + threadIdx.x;
  if (idx >= NN * COUT) return;
  int o = idx & 31;
  float m = gsum[o] * (1.0f / NN);
  float var = gsumsq[o] * (1.0f / NN) - m * m;
  float inv = rsqrtf(var + 1e-5f);
  out[idx] = (out[idx] - m) * inv * gamma[o] + beta[o];
}

extern "C" void kernel_launch(void* const* d_in, const int* in_sizes, int n_in,
                              void* d_out, int out_size, void* d_ws, size_t ws_size,
                              hipStream_t stream) {
  const float* x      = (const float*)d_in[0];
  const int*   ei     = (const int*)d_in[1];
  const float* attr   = (const float*)d_in[2];
  const float* weight = (const float*)d_in[3];
  const float* root   = (const float*)d_in[4];
  const float* bias   = (const float*)d_in[5];
  const float* gamma  = (const float*)d_in[6];
  const float* beta   = (const float*)d_in[7];
  float* out = (float*)d_out;
  char* ws = (char*)d_ws;
  const int* esrc = ei;
  const int* edst = ei + EE;

  int*   hist    = (int*)(ws + W_HIST);
  int*   cursors = (int*)(ws + W_CURS);
  int*   degi    = (int*)(ws + W_DEG);
  float* gsum    = (float*)(ws + W_SUM);
  float* gsumsq  = (float*)(ws + W_SUMSQ);
  int*   offsets = (int*)(ws + W_OFFS);
  int*   sorted  = (int*)(ws + W_SORT);
  unsigned short* wbf = (unsigned short*)(ws + W_WBF);

  hipMemsetAsync(ws, 0, W_ZERO, stream);
  k_wconv<<<250, 256, 0, stream>>>(weight, wbf);
  k_hist<<<512, 256, 0, stream>>>(attr, edst, hist, degi);
  k_scan<<<1, 1024, 0, stream>>>(hist, offsets);
  k_scatter<<<512, 256, 0, stream>>>(attr, edst, offsets, cursors, sorted);
  k_mega<<<NBKT, 512, 0, stream>>>(x, esrc, edst, attr, wbf, sorted, offsets,
                                   degi, root, bias, out, gsum, gsumsq);
  k_bn<<<(NN * COUT) / 256, 256, 0, stream>>>(out, gsum, gsumsq, gamma, beta);
}